// Round 21
// baseline (114.629 us; speedup 1.0000x reference)
//
#include <hip/hip_runtime.h>
#include <math.h>

typedef unsigned short ushort_t;
typedef __attribute__((ext_vector_type(8))) short short8;
typedef __attribute__((ext_vector_type(4))) float f32x4;
typedef __attribute__((ext_vector_type(16))) float f32x16;
typedef __attribute__((ext_vector_type(4))) unsigned short ushort4v;
typedef __attribute__((ext_vector_type(2))) unsigned int uint2v;
typedef __attribute__((ext_vector_type(4))) unsigned int uint4v;

#define D_MODEL 1024
#define SEQ 2048
#define MROWS 4096
#define PLANE (MROWS * D_MODEL)    /* 4194304 elems */
#define WELEM (D_MODEL * D_MODEL)  /* 1048576 elems */

static __device__ __forceinline__ ushort_t f2bf(float f) {
    unsigned u = __builtin_bit_cast(unsigned, f);
    return (ushort_t)((u + 0x7fffu + ((u >> 16) & 1u)) >> 16);
}
static __device__ __forceinline__ unsigned cvtpk(float lo, float hi) {
    unsigned r;
    asm("v_cvt_pk_bf16_f32 %0, %1, %2" : "=v"(r) : "v"(lo), "v"(hi));
    return r;
}
static __device__ __forceinline__ short8 cvt8(float4 a, float4 b) {
    uint4v u = {cvtpk(a.x, a.y), cvtpk(a.z, a.w),
                cvtpk(b.x, b.y), cvtpk(b.z, b.w)};
    return __builtin_bit_cast(short8, u);
}
static __device__ __forceinline__ float max3f(float a, float b, float c) {
    float r;
    asm("v_max3_f32 %0, %1, %2, %3" : "=v"(r) : "v"(a), "v"(b), "v"(c));
    return r;
}

// async global->LDS, 16B per lane; LDS dest = wave-uniform base + lane*16
#define GLDS16(gp, lp)                                                         \
    __builtin_amdgcn_global_load_lds(                                          \
        (const __attribute__((address_space(1))) void*)(gp),                   \
        (__attribute__((address_space(3))) void*)(lp), 16, 0, 0)

// ---------------------------------------------------------------------------
// fp32 -> bf16: WEIGHTS ONLY (inputs are converted in-register by gemm3).
// ---------------------------------------------------------------------------
__global__ __launch_bounds__(256)
void cvt_w(const float* __restrict__ w0, const float* __restrict__ w1,
           const float* __restrict__ w2, const float* __restrict__ w3,
           ushort_t* __restrict__ dst) {
    const int p = blockIdx.x >> 9;
    const float* s = (p == 0) ? w0 : (p == 1) ? w1 : (p == 2) ? w2 : w3;
    const int i = (((int)blockIdx.x & 511) * 256 + threadIdx.x) * 8;
    float4 a = *(const float4*)(s + i);
    float4 bb = *(const float4*)(s + i + 4);
    *(short8*)(dst + (size_t)p * WELEM + i) = cvt8(a, bb);
}

// ---------------------------------------------------------------------------
// Projection GEMM x3 in one launch (z = 0:Q, 1:K, 2:V-transposed).
// R18/R20 config (measured best): BM=64, BN=128, BK=64 -> 24 KB LDS,
// 6 blocks/CU. Fused A-cvt (fp32 -> v_cvt_pk -> swizzled ds_write); B via
// GLDS16 from bf16 weights. 4 waves (2x2): wave owns 32x64. XCD-swizzled.
// ---------------------------------------------------------------------------
__global__ __launch_bounds__(256, 6)
void gemm3(const float* __restrict__ Xq, const float* __restrict__ Xk,
           const float* __restrict__ Xv, const ushort_t* __restrict__ Wb,
           ushort_t* __restrict__ Cb) {
    __shared__ __align__(16) ushort_t As[64 * 64];   // 8 KB
    __shared__ __align__(16) ushort_t Bs[128 * 64];  // 16 KB

    // bijective XCD remap of the 1536-block grid
    const int lin = blockIdx.x + blockIdx.y * 8 + blockIdx.z * 512;
    const int lin2 = (lin & 7) * 192 + (lin >> 3);
    const int z = lin2 >> 9;          // 0..2
    const int rem = lin2 & 511;
    const int by = rem >> 3;          // 0..63
    const int bx = rem & 7;           // 0..7

    const float* A = (z == 0) ? Xq : (z == 1) ? Xk : Xv;
    const ushort_t* B = Wb + (size_t)z * WELEM;
    ushort_t* C = Cb + (size_t)z * PLANE;

    const int tid = threadIdx.x;
    const int lane = tid & 63;
    const int wid = tid >> 6;
    const int wr = wid >> 1, wc = wid & 1;
    const int brow = by * 64;
    const int bcol = bx * 128;

    const int lrow = lane >> 3;
    const int g8 = lane & 7;
    const int loff = (g8 ^ lrow) * 8;  // pre-swizzled source granule

    const float* aF[2];
#pragma unroll
    for (int i = 0; i < 2; ++i)
        aF[i] = A + (size_t)(brow + wid * 16 + i * 8 + lrow) * D_MODEL + loff;
    const ushort_t* bS[4];
#pragma unroll
    for (int i = 0; i < 4; ++i)
        bS[i] = B + (size_t)(bcol + wid * 32 + i * 8 + lrow) * D_MODEL + loff;

    f32x4 acc[2][4];
#pragma unroll
    for (int i = 0; i < 2; ++i)
#pragma unroll
        for (int j = 0; j < 4; ++j) acc[i][j] = {0.f, 0.f, 0.f, 0.f};

    const int fr = lane & 15, fg = lane >> 4;

    // prologue: A fp32 for k0=0 into regs
    float4 ar[2][2];
#pragma unroll
    for (int i = 0; i < 2; ++i) {
        ar[i][0] = *(const float4*)(aF[i]);
        ar[i][1] = *(const float4*)(aF[i] + 4);
    }

    for (int k0 = 0; k0 < D_MODEL; k0 += 64) {
        __syncthreads();  // prior compute reads of As/Bs done
#pragma unroll
        for (int i = 0; i < 2; ++i)
            *(short8*)&As[(wid * 16 + i * 8 + lrow) * 64 + g8 * 8] =
                cvt8(ar[i][0], ar[i][1]);
#pragma unroll
        for (int i = 0; i < 4; ++i)
            GLDS16(bS[i] + k0, Bs + (wid * 32 + i * 8) * 64);
        if (k0 + 64 < D_MODEL) {  // issue next A loads
#pragma unroll
            for (int i = 0; i < 2; ++i) {
                ar[i][0] = *(const float4*)(aF[i] + k0 + 64);
                ar[i][1] = *(const float4*)(aF[i] + k0 + 68);
            }
        }
        __syncthreads();  // staging visible (lgkm + vmcnt drained)
#pragma unroll
        for (int ks = 0; ks < 2; ++ks) {
            const int coff = (ks * 32 + fg * 8) ^ ((fr & 7) << 3);
            short8 af[2], bw[4];
#pragma unroll
            for (int mi = 0; mi < 2; ++mi)
                af[mi] = *(const short8*)&As[(wr * 32 + mi * 16 + fr) * 64 + coff];
#pragma unroll
            for (int nj = 0; nj < 4; ++nj)
                bw[nj] = *(const short8*)&Bs[(wc * 64 + nj * 16 + fr) * 64 + coff];
#pragma unroll
            for (int mi = 0; mi < 2; ++mi)
#pragma unroll
                for (int nj = 0; nj < 4; ++nj)
                    acc[mi][nj] = __builtin_amdgcn_mfma_f32_16x16x32_bf16(
                        af[mi], bw[nj], acc[mi][nj], 0, 0, 0);
        }
    }

    if (z < 2) {  // natural bf16 [m][n]
#pragma unroll
        for (int mi = 0; mi < 2; ++mi)
#pragma unroll
            for (int nj = 0; nj < 4; ++nj) {
                const int n = bcol + wc * 64 + nj * 16 + fr;
#pragma unroll
                for (int r = 0; r < 4; ++r) {
                    const int m = brow + wr * 32 + mi * 16 + fg * 4 + r;
                    C[(size_t)m * D_MODEL + n] = f2bf(acc[mi][nj][r]);
                }
            }
    } else {  // V^T: [b][n][s], s = m % 2048, b = m / 2048
#pragma unroll
        for (int mi = 0; mi < 2; ++mi)
#pragma unroll
            for (int nj = 0; nj < 4; ++nj) {
                const int n = bcol + wc * 64 + nj * 16 + fr;
                const int m0 = brow + wr * 32 + mi * 16 + fg * 4;
                ushort4v o4;
#pragma unroll
                for (int r = 0; r < 4; ++r) o4[r] = f2bf(acc[mi][nj][r]);
                *(ushort4v*)&C[((size_t)(m0 >> 11) << 21) + (size_t)n * SEQ + (m0 & 2047)] = o4;
            }
    }
}

// ---------------------------------------------------------------------------
// Output GEMM (NT, f32 out): 64x128 tile, 24 KB single-buffer, 6 blocks/CU
// (R20 config, measured best). Both operands via GLDS16 (bf16).
// ---------------------------------------------------------------------------
__global__ __launch_bounds__(256, 6)
void gemm_out(const ushort_t* __restrict__ A, const ushort_t* __restrict__ B,
              float* __restrict__ C) {
    __shared__ __align__(16) ushort_t As[64 * 64];   // 8 KB
    __shared__ __align__(16) ushort_t Bs[128 * 64];  // 16 KB

    const int lin = blockIdx.x + blockIdx.y * 8;     // 512 blocks
    const int lin2 = (lin & 7) * 64 + (lin >> 3);
    const int by = lin2 >> 3;   // 0..63
    const int bx = lin2 & 7;    // 0..7

    const int tid = threadIdx.x;
    const int lane = tid & 63;
    const int wid = tid >> 6;
    const int wr = wid >> 1, wc = wid & 1;
    const int brow = by * 64;
    const int bcol = bx * 128;

    const int lrow = lane >> 3;
    const int loff = ((lane & 7) ^ lrow) * 8;

    const ushort_t* aS[2];
#pragma unroll
    for (int i = 0; i < 2; ++i)
        aS[i] = A + (size_t)(brow + wid * 16 + i * 8 + lrow) * D_MODEL + loff;
    const ushort_t* bS[4];
#pragma unroll
    for (int i = 0; i < 4; ++i)
        bS[i] = B + (size_t)(bcol + wid * 32 + i * 8 + lrow) * D_MODEL + loff;

    f32x4 acc[2][4];
#pragma unroll
    for (int i = 0; i < 2; ++i)
#pragma unroll
        for (int j = 0; j < 4; ++j) acc[i][j] = {0.f, 0.f, 0.f, 0.f};

    const int fr = lane & 15, fg = lane >> 4;

    for (int k0 = 0; k0 < D_MODEL; k0 += 64) {
        __syncthreads();
#pragma unroll
        for (int i = 0; i < 2; ++i)
            GLDS16(aS[i] + k0, As + (wid * 16 + i * 8) * 64);
#pragma unroll
        for (int i = 0; i < 4; ++i)
            GLDS16(bS[i] + k0, Bs + (wid * 32 + i * 8) * 64);
        __syncthreads();
#pragma unroll
        for (int ks = 0; ks < 2; ++ks) {
            const int coff = (ks * 32 + fg * 8) ^ ((fr & 7) << 3);
            short8 af[2], bw[4];
#pragma unroll
            for (int mi = 0; mi < 2; ++mi)
                af[mi] = *(const short8*)&As[(wr * 32 + mi * 16 + fr) * 64 + coff];
#pragma unroll
            for (int nj = 0; nj < 4; ++nj)
                bw[nj] = *(const short8*)&Bs[(wc * 64 + nj * 16 + fr) * 64 + coff];
#pragma unroll
            for (int mi = 0; mi < 2; ++mi)
#pragma unroll
                for (int nj = 0; nj < 4; ++nj)
                    acc[mi][nj] = __builtin_amdgcn_mfma_f32_16x16x32_bf16(
                        af[mi], bw[nj], acc[mi][nj], 0, 0, 0);
        }
    }

#pragma unroll
    for (int mi = 0; mi < 2; ++mi)
#pragma unroll
        for (int nj = 0; nj < 4; ++nj) {
            const int n = bcol + wc * 64 + nj * 16 + fr;
#pragma unroll
            for (int r = 0; r < 4; ++r) {
                const int m = brow + wr * 32 + mi * 16 + fg * 4 + r;
                C[(size_t)m * D_MODEL + n] = acc[mi][nj][r];
            }
        }
}

// ---------------------------------------------------------------------------
// bf16 flash attention, 32x32x16 MFMA, split-K wave pairs, 4-deep KV ring
// (two 64-key tiles per barrier). Plateau-verified ~52 us.
// R21 micro: softmax max-reduce via v_max3_f32 tree (8 ops, depth 4;
// was a 15-deep serial fmaxf chain) — T17.
// ---------------------------------------------------------------------------
__global__ __launch_bounds__(512, 4)
void attn_mfma(const ushort_t* __restrict__ Qp, const ushort_t* __restrict__ Kp,
               const ushort_t* __restrict__ VT, ushort_t* __restrict__ Ap) {
    __shared__ __align__(16) ushort_t KB[4][4096];  // K ring, 32 KB
    __shared__ __align__(16) ushort_t VB[4][4096];  // V ring, 32 KB (d-major)
    __shared__ float sm[2][128];                    // per-half row max
    __shared__ float sl[2][128];                    // per-half row l

    const int tid = threadIdx.x;
    const int lane = tid & 63;
    const int wid = tid >> 6;      // 0..7
    const int qgrp = wid & 3;      // q-row group (32 rows)
    const int khalf = wid >> 2;    // key half within each 64-key tile

    // XCD swizzle: 512 blocks -> 64 consecutive per XCD (4 (b,h) pairs).
    const int bid0 = blockIdx.x;
    const int bid = (bid0 & 7) * 64 + (bid0 >> 3);
    const int qt = bid & 15;
    const int h = (bid >> 4) & 15;
    const int b = bid >> 8;

    const int lrow = lane >> 3;
    const int loff = ((lane & 7) ^ lrow) * 8;  // pre-swizzled source granule
    const int q31 = lane & 31;
    const int hi = lane >> 5;

    const int m0 = b * SEQ + qt * 128;  // global q-row base

    // ---- stage Q (wave's 16 rows) into ring slots KB[2..3] ----
    ushort_t* Qstage = &KB[2][0];  // 16 KB region (slots 2,3)
#pragma unroll
    for (int j = 0; j < 2; ++j) {
        const ushort_t* qS =
            Qp + (size_t)(m0 + wid * 16 + j * 8 + lrow) * D_MODEL + h * 64 + loff;
        GLDS16(qS, Qstage + (wid * 16 + j * 8) * 64);
    }
    // ---- stage tiles 0,1 into ring slots 0,1 (one 8-row stripe each) ----
    const ushort_t* kS =
        Kp + (size_t)(b * SEQ + wid * 8 + lrow) * D_MODEL + h * 64 + loff;
    const ushort_t* vS =
        VT + ((size_t)b << 21) + (size_t)(h * 64 + wid * 8 + lrow) * SEQ + loff;
    GLDS16(kS, KB[0] + wid * 512);
    GLDS16(vS, VB[0] + wid * 512);
    kS += 64 * D_MODEL;
    vS += 64;
    GLDS16(kS, KB[1] + wid * 512);
    GLDS16(vS, VB[1] + wid * 512);
    kS += 64 * D_MODEL;
    vS += 64;
    __syncthreads();  // Q + tiles 0,1 landed

    // ---- Q B-frags: lane holds col q, d = 16s + 8hi + j ----
    const int qrow = qgrp * 32 + q31;
    const int rsw = q31 & 7;
    short8 aq[4];
#pragma unroll
    for (int s = 0; s < 4; ++s)
        aq[s] = *(const short8*)&Qstage[qrow * 64 + (((s * 2 + hi) ^ rsw) * 8)];
    __syncthreads();  // all waves read Q -> slots 2,3 recyclable

    f32x16 accO[2];  // O^T partial (this key-half); db selects d 32-block
#pragma unroll
    for (int db = 0; db < 2; ++db)
#pragma unroll
        for (int r = 0; r < 16; ++r) accO[db][r] = 0.f;
    float m_s = -INFINITY;  // running max (log2-scaled domain)
    float l_p = 0.f;        // per-lane partial denominator

    const float CEXP = 0.18033688011112042f;  // log2(e) / sqrt(64)
    const int kbase = khalf * 32;

    int cur = 0;  // ring pair: 0 -> slots {0,1}, 1 -> slots {2,3}
    for (int st = 0; st < SEQ / 128; ++st) {
        // prefetch next pair (2 tiles) into the other ring slots
        if (st + 1 < SEQ / 128) {
            const int b0 = (cur ^ 1) * 2;
            GLDS16(kS, KB[b0] + wid * 512);
            GLDS16(vS, VB[b0] + wid * 512);
            kS += 64 * D_MODEL;
            vS += 64;
            GLDS16(kS, KB[b0 + 1] + wid * 512);
            GLDS16(vS, VB[b0 + 1] + wid * 512);
            kS += 64 * D_MODEL;
            vS += 64;
        }

#pragma unroll
        for (int sub = 0; sub < 2; ++sub) {
            const int bufi = cur * 2 + sub;

            // ---- QK^T over this wave's 32-key half (A=K, B=Q -> C=S^T) ----
            f32x16 accS;
#pragma unroll
            for (int r = 0; r < 16; ++r) accS[r] = 0.f;
            __builtin_amdgcn_s_setprio(1);
#pragma unroll
            for (int s = 0; s < 4; ++s) {
                short8 ak = *(const short8*)&KB[bufi][(kbase + q31) * 64 +
                                                     (((s * 2 + hi) ^ rsw) * 8)];
                accS = __builtin_amdgcn_mfma_f32_32x32x16_bf16(ak, aq[s], accS, 0, 0, 0);
            }
            __builtin_amdgcn_s_setprio(0);

            // ---- softmax: v_max3 tree (8 ops, depth 4) + cross-pair max ----
            float t0 = max3f(accS[0], accS[1], accS[2]);
            float t1 = max3f(accS[3], accS[4], accS[5]);
            float t2 = max3f(accS[6], accS[7], accS[8]);
            float t3 = max3f(accS[9], accS[10], accS[11]);
            float t4 = max3f(accS[12], accS[13], accS[14]);
            float mx = max3f(t0, t1, t2);
            mx = max3f(mx, t3, t4);
            mx = fmaxf(mx, accS[15]);
            mx = fmaxf(mx, __shfl_xor(mx, 32));
            const float cand = mx * CEXP;
            if (__any(cand > m_s + 8.f)) {
                const float mnew = fmaxf(m_s, cand);
                const float al = __builtin_amdgcn_exp2f(m_s - mnew);
                m_s = mnew;
                l_p *= al;
#pragma unroll
                for (int db = 0; db < 2; ++db)
#pragma unroll
                    for (int r = 0; r < 16; ++r) accO[db][r] *= al;
            }
            float ps = 0.f;
            const float nm = -m_s;
#pragma unroll
            for (int r = 0; r < 16; ++r) {
                const float p = __builtin_amdgcn_exp2f(fmaf(accS[r], CEXP, nm));
                accS[r] = p;
                ps += p;
            }
            l_p += ps;

            // ---- P -> PV B-frags in registers (cvt_pk + permlane32_swap) ----
            short8 pf[2];
#pragma unroll
            for (int ks2 = 0; ks2 < 2; ++ks2) {
                const int bse = ks2 * 8;
                unsigned w0 = cvtpk(accS[bse + 0], accS[bse + 1]);
                unsigned w1 = cvtpk(accS[bse + 2], accS[bse + 3]);
                unsigned w2 = cvtpk(accS[bse + 4], accS[bse + 5]);
                unsigned w3 = cvtpk(accS[bse + 6], accS[bse + 7]);
                asm("v_permlane32_swap_b32 %0, %1" : "+v"(w0), "+v"(w2));
                asm("v_permlane32_swap_b32 %0, %1" : "+v"(w1), "+v"(w3));
                uint4v u = {w0, w1, w2, w3};
                pf[ks2] = __builtin_bit_cast(short8, u);
            }

            // ---- PV: O^T[d][q] += V^T[d][k-half] * P[k-half][q] ----
            __builtin_amdgcn_s_setprio(1);
#pragma unroll
            for (int db = 0; db < 2; ++db)
#pragma unroll
                for (int ks2 = 0; ks2 < 2; ++ks2) {
                    short8 av = *(const short8*)&VB[bufi][(db * 32 + q31) * 64 +
                        (((khalf * 4 + ks2 * 2 + hi) ^ rsw) * 8)];
                    accO[db] = __builtin_amdgcn_mfma_f32_32x32x16_bf16(
                        av, pf[ks2], accO[db], 0, 0, 0);
                }
            __builtin_amdgcn_s_setprio(0);
        }
        cur ^= 1;
        __syncthreads();  // next pair staged; this pair's reads done
    }

    // ---- combine the two key-half partials (ring fully retired) ----
    const float lt = l_p + __shfl_xor(l_p, 32);
    const int qg = qgrp * 32 + q31;
    if (lane < 32) {
        sm[khalf][qg] = m_s;
        sl[khalf][qg] = lt;
    }
    __syncthreads();
    const float mA = sm[0][qg], mB = sm[1][qg];
    const float mC = fmaxf(mA, mB);
    const float wA = __builtin_amdgcn_exp2f(mA - mC);
    const float wB = __builtin_amdgcn_exp2f(mB - mC);
    const float inv = 1.0f / (wA * sl[0][qg] + wB * sl[1][qg]);

    float* O1 = (float*)KB;  // 32 KB = 128q x 64d f32, exactly
    if (khalf == 1) {
#pragma unroll
        for (int db = 0; db < 2; ++db)
#pragma unroll
            for (int rq = 0; rq < 4; ++rq) {
                f32x4 v;
#pragma unroll
                for (int j = 0; j < 4; ++j) v[j] = accO[db][rq * 4 + j] * wB;
                const int c = db * 8 + rq * 2 + hi;
                *(f32x4*)&O1[qg * 64 + ((c ^ (q31 & 15)) * 4)] = v;
            }
    }
    __syncthreads();
    unsigned* QsW = (unsigned*)VB;  // 16 KB of the retired V ring
    if (khalf == 0) {
        const int kkw = 2 * (q31 & 15);
#pragma unroll
        for (int db = 0; db < 2; ++db)
#pragma unroll
            for (int rq = 0; rq < 4; ++rq) {
                const int c = db * 8 + rq * 2 + hi;
                f32x4 o1 = *(const f32x4*)&O1[qg * 64 + ((c ^ (q31 & 15)) * 4)];
                float o0 = (accO[db][rq * 4 + 0] * wA + o1[0]) * inv;
                float o1v = (accO[db][rq * 4 + 1] * wA + o1[1]) * inv;
                float o2 = (accO[db][rq * 4 + 2] * wA + o1[2]) * inv;
                float o3 = (accO[db][rq * 4 + 3] * wA + o1[3]) * inv;
                uint2v u = {cvtpk(o0, o1v), cvtpk(o2, o3)};
                const int c0 = 4 * rq + 2 * hi + 16 * db;
                *(uint2v*)&QsW[qg * 32 + (c0 ^ kkw)] = u;
            }
    }
    __syncthreads();
    // ---- coalesced global write: 8 waves x 2 passes x 8 rows ----
#pragma unroll
    for (int pass = 0; pass < 2; ++pass) {
        const int r = wid * 16 + pass * 8 + (lane >> 3);
        const int g8 = lane & 7;
        const int kk = 2 * (r & 15);
        uint2v u0 = *(const uint2v*)&QsW[r * 32 + ((4 * g8) ^ kk)];
        uint2v u1 = *(const uint2v*)&QsW[r * 32 + ((4 * g8 + 2) ^ kk)];
        uint4v o = {u0[0], u0[1], u1[0], u1[1]};
        *(uint4v*)&Ap[(size_t)(m0 + r) * D_MODEL + h * 64 + g8 * 8] = o;
    }
}

// ---------------------------------------------------------------------------
extern "C" void kernel_launch(void* const* d_in, const int* in_sizes, int n_in,
                              void* d_out, int out_size, void* d_ws, size_t ws_size,
                              hipStream_t stream) {
    const float* query = (const float*)d_in[0];
    const float* key   = (const float*)d_in[1];
    const float* value = (const float*)d_in[2];
    const float* W_q   = (const float*)d_in[3];
    const float* W_k   = (const float*)d_in[4];
    const float* W_v   = (const float*)d_in[5];
    const float* W_o   = (const float*)d_in[6];
    float* out = (float*)d_out;

    ushort_t* ws = (ushort_t*)d_ws;
    ushort_t* Wb = ws + 3 * (size_t)PLANE;           // 4 bf16 weights
    ushort_t* Qp = ws + 4 * (size_t)PLANE;           // Q proj (natural)
    ushort_t* Kp = Qp + (size_t)PLANE;               // K proj (natural)
    ushort_t* VT = Kp + (size_t)PLANE;               // V proj (transposed)
    ushort_t* Ap = VT + (size_t)PLANE;               // attention out (natural)
    // total 8 * PLANE * 2B = 67.1 MB (first 3 planes unused)

    cvt_w<<<2048, 256, 0, stream>>>(W_q, W_k, W_v, W_o, Wb);

    dim3 g3(D_MODEL / 128, MROWS / 64, 3);  // (8, 64, 3) = 1536 blocks
    gemm3<<<g3, 256, 0, stream>>>(query, key, value, Wb, Qp);

    attn_mfma<<<512, 512, 0, stream>>>(Qp, Kp, VT, Ap);

    dim3 go(D_MODEL / 128, MROWS / 64);  // (8, 64) = 512 blocks
    gemm_out<<<go, 256, 0, stream>>>(Ap, Wb + 3 * (size_t)WELEM, out);
}

// Round 22
// 113.060 us; speedup vs baseline: 1.0139x; 1.0139x over previous
//
#include <hip/hip_runtime.h>
#include <math.h>

typedef unsigned short ushort_t;
typedef __attribute__((ext_vector_type(8))) short short8;
typedef __attribute__((ext_vector_type(4))) float f32x4;
typedef __attribute__((ext_vector_type(16))) float f32x16;
typedef __attribute__((ext_vector_type(4))) unsigned short ushort4v;
typedef __attribute__((ext_vector_type(2))) unsigned int uint2v;
typedef __attribute__((ext_vector_type(4))) unsigned int uint4v;

#define D_MODEL 1024
#define SEQ 2048
#define MROWS 4096
#define PLANE (MROWS * D_MODEL)    /* 4194304 elems */
#define WELEM (D_MODEL * D_MODEL)  /* 1048576 elems */

static __device__ __forceinline__ ushort_t f2bf(float f) {
    unsigned u = __builtin_bit_cast(unsigned, f);
    return (ushort_t)((u + 0x7fffu + ((u >> 16) & 1u)) >> 16);
}
static __device__ __forceinline__ unsigned cvtpk(float lo, float hi) {
    unsigned r;
    asm("v_cvt_pk_bf16_f32 %0, %1, %2" : "=v"(r) : "v"(lo), "v"(hi));
    return r;
}
static __device__ __forceinline__ short8 cvt8(float4 a, float4 b) {
    uint4v u = {cvtpk(a.x, a.y), cvtpk(a.z, a.w),
                cvtpk(b.x, b.y), cvtpk(b.z, b.w)};
    return __builtin_bit_cast(short8, u);
}

// async global->LDS, 16B per lane; LDS dest = wave-uniform base + lane*16
#define GLDS16(gp, lp)                                                         \
    __builtin_amdgcn_global_load_lds(                                          \
        (const __attribute__((address_space(1))) void*)(gp),                   \
        (__attribute__((address_space(3))) void*)(lp), 16, 0, 0)

// ---------------------------------------------------------------------------
// fp32 -> bf16: WEIGHTS ONLY (inputs are converted in-register by gemm3).
// ---------------------------------------------------------------------------
__global__ __launch_bounds__(256)
void cvt_w(const float* __restrict__ w0, const float* __restrict__ w1,
           const float* __restrict__ w2, const float* __restrict__ w3,
           ushort_t* __restrict__ dst) {
    const int p = blockIdx.x >> 9;
    const float* s = (p == 0) ? w0 : (p == 1) ? w1 : (p == 2) ? w2 : w3;
    const int i = (((int)blockIdx.x & 511) * 256 + threadIdx.x) * 8;
    float4 a = *(const float4*)(s + i);
    float4 bb = *(const float4*)(s + i + 4);
    *(short8*)(dst + (size_t)p * WELEM + i) = cvt8(a, bb);
}

// ---------------------------------------------------------------------------
// Projection GEMM x3 in one launch (z = 0:Q, 1:K, 2:V-transposed).
// Final config (measured best): BM=64, BN=128, BK=64 -> 24 KB LDS,
// 6 blocks/CU (occupancy optimum: 3/6/8 blk/CU = 62/52/68 us measured).
// Fused A-cvt (fp32 -> v_cvt_pk -> swizzled ds_write); B via GLDS16 from
// bf16 weights. 4 waves (2x2): wave owns 32x64. XCD-swizzled.
// ---------------------------------------------------------------------------
__global__ __launch_bounds__(256, 6)
void gemm3(const float* __restrict__ Xq, const float* __restrict__ Xk,
           const float* __restrict__ Xv, const ushort_t* __restrict__ Wb,
           ushort_t* __restrict__ Cb) {
    __shared__ __align__(16) ushort_t As[64 * 64];   // 8 KB
    __shared__ __align__(16) ushort_t Bs[128 * 64];  // 16 KB

    // bijective XCD remap of the 1536-block grid
    const int lin = blockIdx.x + blockIdx.y * 8 + blockIdx.z * 512;
    const int lin2 = (lin & 7) * 192 + (lin >> 3);
    const int z = lin2 >> 9;          // 0..2
    const int rem = lin2 & 511;
    const int by = rem >> 3;          // 0..63
    const int bx = rem & 7;           // 0..7

    const float* A = (z == 0) ? Xq : (z == 1) ? Xk : Xv;
    const ushort_t* B = Wb + (size_t)z * WELEM;
    ushort_t* C = Cb + (size_t)z * PLANE;

    const int tid = threadIdx.x;
    const int lane = tid & 63;
    const int wid = tid >> 6;
    const int wr = wid >> 1, wc = wid & 1;
    const int brow = by * 64;
    const int bcol = bx * 128;

    const int lrow = lane >> 3;
    const int g8 = lane & 7;
    const int loff = (g8 ^ lrow) * 8;  // pre-swizzled source granule

    const float* aF[2];
#pragma unroll
    for (int i = 0; i < 2; ++i)
        aF[i] = A + (size_t)(brow + wid * 16 + i * 8 + lrow) * D_MODEL + loff;
    const ushort_t* bS[4];
#pragma unroll
    for (int i = 0; i < 4; ++i)
        bS[i] = B + (size_t)(bcol + wid * 32 + i * 8 + lrow) * D_MODEL + loff;

    f32x4 acc[2][4];
#pragma unroll
    for (int i = 0; i < 2; ++i)
#pragma unroll
        for (int j = 0; j < 4; ++j) acc[i][j] = {0.f, 0.f, 0.f, 0.f};

    const int fr = lane & 15, fg = lane >> 4;

    // prologue: A fp32 for k0=0 into regs
    float4 ar[2][2];
#pragma unroll
    for (int i = 0; i < 2; ++i) {
        ar[i][0] = *(const float4*)(aF[i]);
        ar[i][1] = *(const float4*)(aF[i] + 4);
    }

    for (int k0 = 0; k0 < D_MODEL; k0 += 64) {
        __syncthreads();  // prior compute reads of As/Bs done
#pragma unroll
        for (int i = 0; i < 2; ++i)
            *(short8*)&As[(wid * 16 + i * 8 + lrow) * 64 + g8 * 8] =
                cvt8(ar[i][0], ar[i][1]);
#pragma unroll
        for (int i = 0; i < 4; ++i)
            GLDS16(bS[i] + k0, Bs + (wid * 32 + i * 8) * 64);
        if (k0 + 64 < D_MODEL) {  // issue next A loads
#pragma unroll
            for (int i = 0; i < 2; ++i) {
                ar[i][0] = *(const float4*)(aF[i] + k0 + 64);
                ar[i][1] = *(const float4*)(aF[i] + k0 + 68);
            }
        }
        __syncthreads();  // staging visible (lgkm + vmcnt drained)
#pragma unroll
        for (int ks = 0; ks < 2; ++ks) {
            const int coff = (ks * 32 + fg * 8) ^ ((fr & 7) << 3);
            short8 af[2], bw[4];
#pragma unroll
            for (int mi = 0; mi < 2; ++mi)
                af[mi] = *(const short8*)&As[(wr * 32 + mi * 16 + fr) * 64 + coff];
#pragma unroll
            for (int nj = 0; nj < 4; ++nj)
                bw[nj] = *(const short8*)&Bs[(wc * 64 + nj * 16 + fr) * 64 + coff];
#pragma unroll
            for (int mi = 0; mi < 2; ++mi)
#pragma unroll
                for (int nj = 0; nj < 4; ++nj)
                    acc[mi][nj] = __builtin_amdgcn_mfma_f32_16x16x32_bf16(
                        af[mi], bw[nj], acc[mi][nj], 0, 0, 0);
        }
    }

    if (z < 2) {  // natural bf16 [m][n]
#pragma unroll
        for (int mi = 0; mi < 2; ++mi)
#pragma unroll
            for (int nj = 0; nj < 4; ++nj) {
                const int n = bcol + wc * 64 + nj * 16 + fr;
#pragma unroll
                for (int r = 0; r < 4; ++r) {
                    const int m = brow + wr * 32 + mi * 16 + fg * 4 + r;
                    C[(size_t)m * D_MODEL + n] = f2bf(acc[mi][nj][r]);
                }
            }
    } else {  // V^T: [b][n][s], s = m % 2048, b = m / 2048
#pragma unroll
        for (int mi = 0; mi < 2; ++mi)
#pragma unroll
            for (int nj = 0; nj < 4; ++nj) {
                const int n = bcol + wc * 64 + nj * 16 + fr;
                const int m0 = brow + wr * 32 + mi * 16 + fg * 4;
                ushort4v o4;
#pragma unroll
                for (int r = 0; r < 4; ++r) o4[r] = f2bf(acc[mi][nj][r]);
                *(ushort4v*)&C[((size_t)(m0 >> 11) << 21) + (size_t)n * SEQ + (m0 & 2047)] = o4;
            }
    }
}

// ---------------------------------------------------------------------------
// Output GEMM (NT, f32 out): 64x128 tile, 24 KB single-buffer, 6 blocks/CU
// (measured best). Both operands via GLDS16 (bf16).
// ---------------------------------------------------------------------------
__global__ __launch_bounds__(256, 6)
void gemm_out(const ushort_t* __restrict__ A, const ushort_t* __restrict__ B,
              float* __restrict__ C) {
    __shared__ __align__(16) ushort_t As[64 * 64];   // 8 KB
    __shared__ __align__(16) ushort_t Bs[128 * 64];  // 16 KB

    const int lin = blockIdx.x + blockIdx.y * 8;     // 512 blocks
    const int lin2 = (lin & 7) * 64 + (lin >> 3);
    const int by = lin2 >> 3;   // 0..63
    const int bx = lin2 & 7;    // 0..7

    const int tid = threadIdx.x;
    const int lane = tid & 63;
    const int wid = tid >> 6;
    const int wr = wid >> 1, wc = wid & 1;
    const int brow = by * 64;
    const int bcol = bx * 128;

    const int lrow = lane >> 3;
    const int loff = ((lane & 7) ^ lrow) * 8;

    const ushort_t* aS[2];
#pragma unroll
    for (int i = 0; i < 2; ++i)
        aS[i] = A + (size_t)(brow + wid * 16 + i * 8 + lrow) * D_MODEL + loff;
    const ushort_t* bS[4];
#pragma unroll
    for (int i = 0; i < 4; ++i)
        bS[i] = B + (size_t)(bcol + wid * 32 + i * 8 + lrow) * D_MODEL + loff;

    f32x4 acc[2][4];
#pragma unroll
    for (int i = 0; i < 2; ++i)
#pragma unroll
        for (int j = 0; j < 4; ++j) acc[i][j] = {0.f, 0.f, 0.f, 0.f};

    const int fr = lane & 15, fg = lane >> 4;

    for (int k0 = 0; k0 < D_MODEL; k0 += 64) {
        __syncthreads();
#pragma unroll
        for (int i = 0; i < 2; ++i)
            GLDS16(aS[i] + k0, As + (wid * 16 + i * 8) * 64);
#pragma unroll
        for (int i = 0; i < 4; ++i)
            GLDS16(bS[i] + k0, Bs + (wid * 32 + i * 8) * 64);
        __syncthreads();
#pragma unroll
        for (int ks = 0; ks < 2; ++ks) {
            const int coff = (ks * 32 + fg * 8) ^ ((fr & 7) << 3);
            short8 af[2], bw[4];
#pragma unroll
            for (int mi = 0; mi < 2; ++mi)
                af[mi] = *(const short8*)&As[(wr * 32 + mi * 16 + fr) * 64 + coff];
#pragma unroll
            for (int nj = 0; nj < 4; ++nj)
                bw[nj] = *(const short8*)&Bs[(wc * 64 + nj * 16 + fr) * 64 + coff];
#pragma unroll
            for (int mi = 0; mi < 2; ++mi)
#pragma unroll
                for (int nj = 0; nj < 4; ++nj)
                    acc[mi][nj] = __builtin_amdgcn_mfma_f32_16x16x32_bf16(
                        af[mi], bw[nj], acc[mi][nj], 0, 0, 0);
        }
    }

#pragma unroll
    for (int mi = 0; mi < 2; ++mi)
#pragma unroll
        for (int nj = 0; nj < 4; ++nj) {
            const int n = bcol + wc * 64 + nj * 16 + fr;
#pragma unroll
            for (int r = 0; r < 4; ++r) {
                const int m = brow + wr * 32 + mi * 16 + fg * 4 + r;
                C[(size_t)m * D_MODEL + n] = acc[mi][nj][r];
            }
        }
}

// ---------------------------------------------------------------------------
// bf16 flash attention, 32x32x16 MFMA, split-K wave pairs, 4-deep KV ring
// (two 64-key tiles per barrier). Plateau-verified ~52 us (5 structural
// perturbations all neutral-or-worse; dependency-bound, no pipe saturated).
// ---------------------------------------------------------------------------
__global__ __launch_bounds__(512, 4)
void attn_mfma(const ushort_t* __restrict__ Qp, const ushort_t* __restrict__ Kp,
               const ushort_t* __restrict__ VT, ushort_t* __restrict__ Ap) {
    __shared__ __align__(16) ushort_t KB[4][4096];  // K ring, 32 KB
    __shared__ __align__(16) ushort_t VB[4][4096];  // V ring, 32 KB (d-major)
    __shared__ float sm[2][128];                    // per-half row max
    __shared__ float sl[2][128];                    // per-half row l

    const int tid = threadIdx.x;
    const int lane = tid & 63;
    const int wid = tid >> 6;      // 0..7
    const int qgrp = wid & 3;      // q-row group (32 rows)
    const int khalf = wid >> 2;    // key half within each 64-key tile

    // XCD swizzle: 512 blocks -> 64 consecutive per XCD (4 (b,h) pairs).
    const int bid0 = blockIdx.x;
    const int bid = (bid0 & 7) * 64 + (bid0 >> 3);
    const int qt = bid & 15;
    const int h = (bid >> 4) & 15;
    const int b = bid >> 8;

    const int lrow = lane >> 3;
    const int loff = ((lane & 7) ^ lrow) * 8;  // pre-swizzled source granule
    const int q31 = lane & 31;
    const int hi = lane >> 5;

    const int m0 = b * SEQ + qt * 128;  // global q-row base

    // ---- stage Q (wave's 16 rows) into ring slots KB[2..3] ----
    ushort_t* Qstage = &KB[2][0];  // 16 KB region (slots 2,3)
#pragma unroll
    for (int j = 0; j < 2; ++j) {
        const ushort_t* qS =
            Qp + (size_t)(m0 + wid * 16 + j * 8 + lrow) * D_MODEL + h * 64 + loff;
        GLDS16(qS, Qstage + (wid * 16 + j * 8) * 64);
    }
    // ---- stage tiles 0,1 into ring slots 0,1 (one 8-row stripe each) ----
    const ushort_t* kS =
        Kp + (size_t)(b * SEQ + wid * 8 + lrow) * D_MODEL + h * 64 + loff;
    const ushort_t* vS =
        VT + ((size_t)b << 21) + (size_t)(h * 64 + wid * 8 + lrow) * SEQ + loff;
    GLDS16(kS, KB[0] + wid * 512);
    GLDS16(vS, VB[0] + wid * 512);
    kS += 64 * D_MODEL;
    vS += 64;
    GLDS16(kS, KB[1] + wid * 512);
    GLDS16(vS, VB[1] + wid * 512);
    kS += 64 * D_MODEL;
    vS += 64;
    __syncthreads();  // Q + tiles 0,1 landed

    // ---- Q B-frags: lane holds col q, d = 16s + 8hi + j ----
    const int qrow = qgrp * 32 + q31;
    const int rsw = q31 & 7;
    short8 aq[4];
#pragma unroll
    for (int s = 0; s < 4; ++s)
        aq[s] = *(const short8*)&Qstage[qrow * 64 + (((s * 2 + hi) ^ rsw) * 8)];
    __syncthreads();  // all waves read Q -> slots 2,3 recyclable

    f32x16 accO[2];  // O^T partial (this key-half); db selects d 32-block
#pragma unroll
    for (int db = 0; db < 2; ++db)
#pragma unroll
        for (int r = 0; r < 16; ++r) accO[db][r] = 0.f;
    float m_s = -INFINITY;  // running max (log2-scaled domain)
    float l_p = 0.f;        // per-lane partial denominator

    const float CEXP = 0.18033688011112042f;  // log2(e) / sqrt(64)
    const int kbase = khalf * 32;

    int cur = 0;  // ring pair: 0 -> slots {0,1}, 1 -> slots {2,3}
    for (int st = 0; st < SEQ / 128; ++st) {
        // prefetch next pair (2 tiles) into the other ring slots
        if (st + 1 < SEQ / 128) {
            const int b0 = (cur ^ 1) * 2;
            GLDS16(kS, KB[b0] + wid * 512);
            GLDS16(vS, VB[b0] + wid * 512);
            kS += 64 * D_MODEL;
            vS += 64;
            GLDS16(kS, KB[b0 + 1] + wid * 512);
            GLDS16(vS, VB[b0 + 1] + wid * 512);
            kS += 64 * D_MODEL;
            vS += 64;
        }

#pragma unroll
        for (int sub = 0; sub < 2; ++sub) {
            const int bufi = cur * 2 + sub;

            // ---- QK^T over this wave's 32-key half (A=K, B=Q -> C=S^T) ----
            f32x16 accS;
#pragma unroll
            for (int r = 0; r < 16; ++r) accS[r] = 0.f;
            __builtin_amdgcn_s_setprio(1);
#pragma unroll
            for (int s = 0; s < 4; ++s) {
                short8 ak = *(const short8*)&KB[bufi][(kbase + q31) * 64 +
                                                     (((s * 2 + hi) ^ rsw) * 8)];
                accS = __builtin_amdgcn_mfma_f32_32x32x16_bf16(ak, aq[s], accS, 0, 0, 0);
            }
            __builtin_amdgcn_s_setprio(0);

            // ---- softmax: 16 in-lane scores + one cross-pair max ----
            float mx = accS[0];
#pragma unroll
            for (int r = 1; r < 16; ++r) mx = fmaxf(mx, accS[r]);
            mx = fmaxf(mx, __shfl_xor(mx, 32));
            const float cand = mx * CEXP;
            if (__any(cand > m_s + 8.f)) {
                const float mnew = fmaxf(m_s, cand);
                const float al = __builtin_amdgcn_exp2f(m_s - mnew);
                m_s = mnew;
                l_p *= al;
#pragma unroll
                for (int db = 0; db < 2; ++db)
#pragma unroll
                    for (int r = 0; r < 16; ++r) accO[db][r] *= al;
            }
            float ps = 0.f;
            const float nm = -m_s;
#pragma unroll
            for (int r = 0; r < 16; ++r) {
                const float p = __builtin_amdgcn_exp2f(fmaf(accS[r], CEXP, nm));
                accS[r] = p;
                ps += p;
            }
            l_p += ps;

            // ---- P -> PV B-frags in registers (cvt_pk + permlane32_swap) ----
            short8 pf[2];
#pragma unroll
            for (int ks2 = 0; ks2 < 2; ++ks2) {
                const int bse = ks2 * 8;
                unsigned w0 = cvtpk(accS[bse + 0], accS[bse + 1]);
                unsigned w1 = cvtpk(accS[bse + 2], accS[bse + 3]);
                unsigned w2 = cvtpk(accS[bse + 4], accS[bse + 5]);
                unsigned w3 = cvtpk(accS[bse + 6], accS[bse + 7]);
                asm("v_permlane32_swap_b32 %0, %1" : "+v"(w0), "+v"(w2));
                asm("v_permlane32_swap_b32 %0, %1" : "+v"(w1), "+v"(w3));
                uint4v u = {w0, w1, w2, w3};
                pf[ks2] = __builtin_bit_cast(short8, u);
            }

            // ---- PV: O^T[d][q] += V^T[d][k-half] * P[k-half][q] ----
            __builtin_amdgcn_s_setprio(1);
#pragma unroll
            for (int db = 0; db < 2; ++db)
#pragma unroll
                for (int ks2 = 0; ks2 < 2; ++ks2) {
                    short8 av = *(const short8*)&VB[bufi][(db * 32 + q31) * 64 +
                        (((khalf * 4 + ks2 * 2 + hi) ^ rsw) * 8)];
                    accO[db] = __builtin_amdgcn_mfma_f32_32x32x16_bf16(
                        av, pf[ks2], accO[db], 0, 0, 0);
                }
            __builtin_amdgcn_s_setprio(0);
        }
        cur ^= 1;
        __syncthreads();  // next pair staged; this pair's reads done
    }

    // ---- combine the two key-half partials (ring fully retired) ----
    const float lt = l_p + __shfl_xor(l_p, 32);
    const int qg = qgrp * 32 + q31;
    if (lane < 32) {
        sm[khalf][qg] = m_s;
        sl[khalf][qg] = lt;
    }
    __syncthreads();
    const float mA = sm[0][qg], mB = sm[1][qg];
    const float mC = fmaxf(mA, mB);
    const float wA = __builtin_amdgcn_exp2f(mA - mC);
    const float wB = __builtin_amdgcn_exp2f(mB - mC);
    const float inv = 1.0f / (wA * sl[0][qg] + wB * sl[1][qg]);

    float* O1 = (float*)KB;  // 32 KB = 128q x 64d f32, exactly
    if (khalf == 1) {
#pragma unroll
        for (int db = 0; db < 2; ++db)
#pragma unroll
            for (int rq = 0; rq < 4; ++rq) {
                f32x4 v;
#pragma unroll
                for (int j = 0; j < 4; ++j) v[j] = accO[db][rq * 4 + j] * wB;
                const int c = db * 8 + rq * 2 + hi;
                *(f32x4*)&O1[qg * 64 + ((c ^ (q31 & 15)) * 4)] = v;
            }
    }
    __syncthreads();
    unsigned* QsW = (unsigned*)VB;  // 16 KB of the retired V ring
    if (khalf == 0) {
        const int kkw = 2 * (q31 & 15);
#pragma unroll
        for (int db = 0; db < 2; ++db)
#pragma unroll
            for (int rq = 0; rq < 4; ++rq) {
                const int c = db * 8 + rq * 2 + hi;
                f32x4 o1 = *(const f32x4*)&O1[qg * 64 + ((c ^ (q31 & 15)) * 4)];
                float o0 = (accO[db][rq * 4 + 0] * wA + o1[0]) * inv;
                float o1v = (accO[db][rq * 4 + 1] * wA + o1[1]) * inv;
                float o2 = (accO[db][rq * 4 + 2] * wA + o1[2]) * inv;
                float o3 = (accO[db][rq * 4 + 3] * wA + o1[3]) * inv;
                uint2v u = {cvtpk(o0, o1v), cvtpk(o2, o3)};
                const int c0 = 4 * rq + 2 * hi + 16 * db;
                *(uint2v*)&QsW[qg * 32 + (c0 ^ kkw)] = u;
            }
    }
    __syncthreads();
    // ---- coalesced global write: 8 waves x 2 passes x 8 rows ----
#pragma unroll
    for (int pass = 0; pass < 2; ++pass) {
        const int r = wid * 16 + pass * 8 + (lane >> 3);
        const int g8 = lane & 7;
        const int kk = 2 * (r & 15);
        uint2v u0 = *(const uint2v*)&QsW[r * 32 + ((4 * g8) ^ kk)];
        uint2v u1 = *(const uint2v*)&QsW[r * 32 + ((4 * g8 + 2) ^ kk)];
        uint4v o = {u0[0], u0[1], u1[0], u1[1]};
        *(uint4v*)&Ap[(size_t)(m0 + r) * D_MODEL + h * 64 + g8 * 8] = o;
    }
}

// ---------------------------------------------------------------------------
extern "C" void kernel_launch(void* const* d_in, const int* in_sizes, int n_in,
                              void* d_out, int out_size, void* d_ws, size_t ws_size,
                              hipStream_t stream) {
    const float* query = (const float*)d_in[0];
    const float* key   = (const float*)d_in[1];
    const float* value = (const float*)d_in[2];
    const float* W_q   = (const float*)d_in[3];
    const float* W_k   = (const float*)d_in[4];
    const float* W_v   = (const float*)d_in[5];
    const float* W_o   = (const float*)d_in[6];
    float* out = (float*)d_out;

    ushort_t* ws = (ushort_t*)d_ws;
    ushort_t* Wb = ws + 3 * (size_t)PLANE;           // 4 bf16 weights
    ushort_t* Qp = ws + 4 * (size_t)PLANE;           // Q proj (natural)
    ushort_t* Kp = Qp + (size_t)PLANE;               // K proj (natural)
    ushort_t* VT = Kp + (size_t)PLANE;               // V proj (transposed)
    ushort_t* Ap = VT + (size_t)PLANE;               // attention out (natural)
    // total 8 * PLANE * 2B = 67.1 MB (first 3 planes unused)

    cvt_w<<<2048, 256, 0, stream>>>(W_q, W_k, W_v, W_o, Wb);

    dim3 g3(D_MODEL / 128, MROWS / 64, 3);  // (8, 64, 3) = 1536 blocks
    gemm3<<<g3, 256, 0, stream>>>(query, key, value, Wb, Qp);

    attn_mfma<<<512, 512, 0, stream>>>(Qp, Kp, VT, Ap);

    dim3 go(D_MODEL / 128, MROWS / 64);  // (8, 64) = 512 blocks
    gemm_out<<<go, 256, 0, stream>>>(Ap, Wb + 3 * (size_t)WELEM, out);
}